// Round 13
// baseline (668.683 us; speedup 1.0000x reference)
//
#include <hip/hip_runtime.h>
#include <hip/hip_bf16.h>

// Problem constants
#define B_ 128
#define S_ 128
#define W_ 16
#define V_ 128
#define H_ 512
#define L_ 64

typedef _Float16 f16x8 __attribute__((ext_vector_type(8)));
typedef float f32x4 __attribute__((ext_vector_type(4)));

__device__ __forceinline__ float sigm(float v) { return 1.0f / (1.0f + __expf(-v)); }
__device__ __forceinline__ float tanhf_(float v) { return 1.0f - 2.0f / (1.0f + __expf(2.0f * v)); }

__device__ __forceinline__ unsigned short f16bits(_Float16 h) {
    return __builtin_bit_cast(unsigned short, h);
}

// ---------------------------------------------------------------------------
// Workspace layout (bytes):
//   hbuf  u32 packed(hi,lo) [par2][dir2][128][512] @ 0        (1048576)
//   (dead slots/flag)                              @ 1048576
//   xhi   u16 [128][128][128]                      @ 1065024  (4194304)
//   xlo   u16 [128][128][128]                      @ 5259328  (4194304)
//   whalf f16 [1966080]                            @ 9453632  (3932160)
//         [whhf 786432 | whhb 786432 | wihf 196608 | wihb 196608]
//   smallF f32 [71745]                             @ 13385792 (287040)
//         [bihf 1536|bhhf 1536|bihb 1536|bhhb 1536|wlin 65536|blin 64|fg 1]
//   Ycat  f16 [128][128][1024]                     @ 13672832 (33554432)
//   wlinh f16 [64][1024]                           @ 47227264 (131072)
//   wlinl f16 [64][1024]                           @ 47358336 (131072) -> ends 47489408
// ---------------------------------------------------------------------------
#define OFF_XHI   1065024
#define OFF_XLO   5259328
#define OFF_WH    9453632
#define OFF_SMALL 13385792
#define OFF_YCAT  13672832
#define OFF_WLH   47227264
#define OFF_WLL   47358336

// ---------------------------------------------------------------------------
// R22 prep (= R21 prep, kept): ALL prep + hbuf zeroing fused into ONE
// dispatch; dtype flag computed per-block (deterministic ballot vote over
// the same 256 words of Whhf).
//   bid <  7680           : whalf canonicalization (fp16 RTN)
//   bid <  7961           : biases/W_lin/b_lin/forget -> fp32
//   bid <  8217           : W_lin hi/lo f16 planes
//   bid < 16409           : FOFE -> xhi/xlo
//   else (1024 blocks)    : zero hbuf (tag bits = 0; visible to gru via
//                           kernel-boundary release->acquire)
// ---------------------------------------------------------------------------
__global__ void prep_all(const void* __restrict__ whhf, const void* __restrict__ whhb,
                         const void* __restrict__ wihf, const void* __restrict__ wihb,
                         const void* __restrict__ bihf, const void* __restrict__ bhhf,
                         const void* __restrict__ bihb, const void* __restrict__ bhhb,
                         const void* __restrict__ wlin, const void* __restrict__ blin,
                         const void* __restrict__ fgp, const int* __restrict__ chars,
                         _Float16* __restrict__ whalf, float* __restrict__ smallF,
                         _Float16* __restrict__ whi, _Float16* __restrict__ wlo,
                         unsigned short* __restrict__ xhi, unsigned short* __restrict__ xlo,
                         unsigned* __restrict__ hbuf) {
    const int bid = blockIdx.x;
    const int tid = threadIdx.x;
    const int wave = tid >> 6;
    const int lane = tid & 63;

    if (bid >= 16409) {  // hbuf zeroing: 1024 blocks x 1KB
        hbuf[(bid - 16409) * 256 + tid] = 0u;
        return;
    }

    // ---- per-block dtype vote (identical inputs -> identical result) ----
    __shared__ int wv[4];
    {
        unsigned word = ((const unsigned*)whhf)[tid];
        unsigned e = (word >> 7) & 0xFFu;
        unsigned long long m = __ballot(e >= 64u && e <= 126u);
        if (lane == 0) wv[wave] = __popcll(m);
    }
    __syncthreads();
    const int fl = (wv[0] + wv[1] + wv[2] + wv[3] >= 160) ? 1 : 0;  // 1 = bf16

    if (bid < 7680) {
        int i = bid * 256 + tid;  // 1966080 exactly
        const void* src;
        int off;
        if (i < 786432)       { src = whhf; off = i; }
        else if (i < 1572864) { src = whhb; off = i - 786432; }
        else if (i < 1769472) { src = wihf; off = i - 1572864; }
        else                  { src = wihb; off = i - 1769472; }
        float v = fl ? __bfloat162float(((const __hip_bfloat16*)src)[off])
                     : ((const float*)src)[off];
        whalf[i] = (_Float16)v;
    } else if (bid < 7961) {
        int i = (bid - 7680) * 256 + tid;
        if (i >= 71745) return;
        const void* src;
        int off;
        if (i < 1536)       { src = bihf; off = i; }
        else if (i < 3072)  { src = bhhf; off = i - 1536; }
        else if (i < 4608)  { src = bihb; off = i - 3072; }
        else if (i < 6144)  { src = bhhb; off = i - 4608; }
        else if (i < 71680) { src = wlin; off = i - 6144; }
        else if (i < 71744) { src = blin; off = i - 71680; }
        else                { src = fgp;  off = 0; }
        float v = fl ? __bfloat162float(((const __hip_bfloat16*)src)[off])
                     : ((const float*)src)[off];
        smallF[i] = v;
    } else if (bid < 8217) {
        int i = (bid - 7961) * 256 + tid;  // 65536
        float v = fl ? __bfloat162float(((const __hip_bfloat16*)wlin)[i])
                     : ((const float*)wlin)[i];
        _Float16 hi = (_Float16)v;
        whi[i] = hi;
        wlo[i] = (_Float16)(v - (float)hi);
    } else {
        // FOFE: 2 positions per block
        __shared__ int cS[2][W_];
        const int fb = bid - 8217;
        int sub = tid >> 7;
        int v = tid & 127;
        int bi = fb * 2 + sub;  // b*S + s
        if (v < W_) cS[sub][v] = chars[bi * W_ + v];
        __syncthreads();
        float f = fl ? __bfloat162float(*(const __hip_bfloat16*)fgp)
                     : *(const float*)fgp;
        float wt[W_];
        float cur = 1.0f;
#pragma unroll
        for (int w = W_ - 1; w >= 0; --w) {
            bool m = (cS[sub][w] != 0);
            wt[w] = m ? cur : 0.0f;
            if (m) cur *= f;
        }
        float acc = 0.0f;
#pragma unroll
        for (int w = 0; w < W_; ++w) acc += (cS[sub][w] == v) ? wt[w] : 0.0f;
        _Float16 hi = (_Float16)acc;
        _Float16 lo = (_Float16)(acc - (float)hi);
        xhi[(size_t)bi * V_ + v] = f16bits(hi);
        xlo[(size_t)bi * V_ + v] = f16bits(lo);
    }
}

// ---------------------------------------------------------------------------
// Persistent bidirectional GRU.
// R22 = R18 champion EXACT (measured 478us):
//   - Tagged fire-and-forget exchange: h word donates lo-plane LSB (bit16)
//     as step tag, tag(t)=((t>>1)&1)^1. Producer: tagged relaxed-agent
//     atomic stores right after gates. Consumer: full 16-word volley of
//     relaxed agent u64 loads, single pending mask, re-load only stale.
//   - Same-step coalesced x staging (tid-based transport).
//   - LDS double-buffer (parity-indexed), single barrier per step (WAR on
//     buffer[par]@t covered by barrier A of t+1 — R18 proof).
// REVERTED (all measured regressions): R19 x-scatter (-69us), R20
// x-prefetch-LDS (-11us), R21 half-volley polling (-67us). Three failed
// refinements => R18's step time is the structural floor for this
// decomposition: slowest-of-8-peers store-landing + one volley observation
// + ~1us work, at 1 MALL-resident exchange per dependent step.
// (8 blocks/chain is forced: 245KB weights/block is the register-residency
// limit; fewer blocks would stream 2MB/chain/step from L2 — far worse.)
// ---------------------------------------------------------------------------
__launch_bounds__(256, 1)
__global__ void gru_kernel(const int* __restrict__ lengths,
                           const _Float16* __restrict__ wh,
                           const float* __restrict__ biasF,
                           const unsigned short* __restrict__ xhi,
                           const unsigned short* __restrict__ xlo,
                           unsigned* __restrict__ hbuf,
                           _Float16* __restrict__ Ycat) {
    constexpr int RSTR = 656;  // 640 + 16 pad halves (0 conflicts measured r5/r7)
    __shared__ _Float16 Ahi[2][16 * RSTR];
    __shared__ _Float16 Alo[2][16 * RSTR];
    __shared__ int lenS[16];

    const int tid = threadIdx.x;
    const int chain = blockIdx.x & 15;
    const int blk = blockIdx.x >> 4;    // 0..7
    const int d = chain & 1;
    const int bg = chain >> 1;
    const int b0 = bg * 16;
    const int wave = tid >> 6;          // 0..3
    const int lane = tid & 63;
    const int quad = lane >> 4;
    const int col = lane & 15;
    const int j0w = (blk * 4 + wave) * 16;  // 0..496

    const _Float16* Whh = wh + (d ? 786432 : 0);
    const _Float16* Wih = wh + 1572864 + (d ? 196608 : 0);
    const float* bih = biasF + (d ? 3072 : 0);
    const float* bhh = biasF + 1536 + (d ? 3072 : 0);

    if (tid < 16) lenS[tid] = lengths[b0 + tid];
    __syncthreads();

    const int g_r = j0w + col;  // r row; z = 512+g_r; n = 1024+g_r

    // Persistent B fragments: lane holds W[g][kk*32 + quad*8 + 0..7]
    f16x8 br[20], bz[20], bn[20];
#pragma unroll
    for (int kk = 0; kk < 16; ++kk) {
        int k = kk * 32 + quad * 8;
        br[kk] = *(const f16x8*)(Whh + (size_t)(g_r)*H_ + k);
        bz[kk] = *(const f16x8*)(Whh + (size_t)(512 + g_r) * H_ + k);
        bn[kk] = *(const f16x8*)(Whh + (size_t)(1024 + g_r) * H_ + k);
    }
#pragma unroll
    for (int kk = 16; kk < 20; ++kk) {
        int k = (kk - 16) * 32 + quad * 8;
        br[kk] = *(const f16x8*)(Wih + (size_t)(g_r)*V_ + k);
        bz[kk] = *(const f16x8*)(Wih + (size_t)(512 + g_r) * V_ + k);
        bn[kk] = *(const f16x8*)(Wih + (size_t)(1024 + g_r) * V_ + k);
    }

    const float bias_r = bih[g_r] + bhh[g_r];
    const float bias_z = bih[512 + g_r] + bhh[512 + g_r];
    const float bihn = bih[1024 + g_r];
    const float bhhn = bhh[1024 + g_r];

    int len4[4];
#pragma unroll
    for (int i = 0; i < 4; ++i) len4[i] = lenS[quad * 4 + i];
    const int maxlen = lenS[0];  // lengths sorted descending

    float h_own[4] = {0.f, 0.f, 0.f, 0.f};  // fp32 master state (b=quad*4+i, j=col)

    // x staging: 16 rows x 16 chunks of 8 halves (int4 per plane per thread)
    const int xb = tid >> 4;
    const int xv8 = (tid & 15) * 8;

    const unsigned long long tagMsk = (1ULL << 16) | (1ULL << 48);

    for (int t = 0; t < S_; ++t) {
        if (t < maxlen) {
            const int par = t & 1;
            const _Float16* arh = &Ahi[par][col * RSTR + quad * 8];
            const _Float16* arl = &Alo[par][col * RSTR + quad * 8];
            // ---- x loads (plain cached, RO; issued first, overlap volley) ----
            int lxb = lenS[xb];
            int sxb = d ? max(0, lxb - 1 - t) : t;
            int4 xh4 = *(const int4*)(xhi + ((size_t)(b0 + xb) * S_ + sxb) * V_ + xv8);
            int4 xl4 = *(const int4*)(xlo + ((size_t)(b0 + xb) * S_ + sxb) * V_ + xv8);

            // ---- h gather: tag-validated volley of relaxed agent u64 loads.
            //      Row i = batch i, col-pair (2*tid, 2*tid+1). ----
            unsigned* hrp = hbuf + ((size_t)(par * 2 + d) * B_ + b0) * H_;
            unsigned long long hv[16];
            if (t > 0) {
                const unsigned te = ((((unsigned)(t - 1)) >> 1) & 1u) ^ 1u;
                const unsigned long long tagPat =
                    ((unsigned long long)te << 16) | ((unsigned long long)te << 48);
                unsigned pend = 0xFFFFu;
                unsigned round = 0;
#pragma unroll
                for (int i = 0; i < 16; ++i)
                    hv[i] = __hip_atomic_load(
                        (const unsigned long long*)(hrp + (size_t)i * H_ + tid * 2),
                        __ATOMIC_RELAXED, __HIP_MEMORY_SCOPE_AGENT);
                while (true) {
                    unsigned np = 0;
#pragma unroll
                    for (int i = 0; i < 16; ++i)
                        if ((pend & (1u << i)) && (hv[i] & tagMsk) != tagPat) np |= (1u << i);
                    if (!np) break;
#pragma unroll
                    for (int i = 0; i < 16; ++i)
                        if (np & (1u << i))
                            hv[i] = __hip_atomic_load(
                                (const unsigned long long*)(hrp + (size_t)i * H_ + tid * 2),
                                __ATOMIC_RELAXED, __HIP_MEMORY_SCOPE_AGENT);
                    pend = np;
                    ++round;
                    if (round > 4u) __builtin_amdgcn_s_sleep(1);
                    if ((round & 31u) == 31u)  // stale-L2 insurance; free if unused
                        __builtin_amdgcn_fence(__ATOMIC_ACQUIRE, "agent");
                    if (round > 400000u) break;  // malfunction -> visible failure
                }
            } else {
                // t=0: initial h is all zeros — no loads needed
#pragma unroll
                for (int i = 0; i < 16; ++i) hv[i] = 0ULL;
            }

            // ---- stage x into LDS[par] ----
            *(int4*)&Ahi[par][xb * RSTR + 512 + xv8] = xh4;
            *(int4*)&Alo[par][xb * RSTR + 512 + xv8] = xl4;
            // ---- unpack h (clear tag bits) and stage into LDS[par] ----
#pragma unroll
            for (int i = 0; i < 16; ++i) {
                unsigned p0 = (unsigned)hv[i];
                unsigned p1 = (unsigned)(hv[i] >> 32);
                unsigned hi2 = (p0 & 0xffffu) | (p1 << 16);
                unsigned lo2 = ((p0 >> 16) | (p1 & 0xffff0000u)) & ~0x00010001u;
                *(unsigned*)&Ahi[par][i * RSTR + tid * 2] = hi2;
                *(unsigned*)&Alo[par][i * RSTR + tid * 2] = lo2;
            }
            __syncthreads();  // A: staging complete (only barrier per step)

            // ---- MFMA: hw = (h_hi + h_lo) @ W^T (fp16 in, fp32 acc) ----
            f32x4 accr = {0.f, 0.f, 0.f, 0.f};
            f32x4 accz = {0.f, 0.f, 0.f, 0.f};
            f32x4 acchn = {0.f, 0.f, 0.f, 0.f};
            f32x4 accxn = {0.f, 0.f, 0.f, 0.f};
#pragma unroll
            for (int kk = 0; kk < 16; ++kk) {
                f16x8 ah = *(const f16x8*)(arh + kk * 32);
                f16x8 al = *(const f16x8*)(arl + kk * 32);
                accr = __builtin_amdgcn_mfma_f32_16x16x32_f16(ah, br[kk], accr, 0, 0, 0);
                accr = __builtin_amdgcn_mfma_f32_16x16x32_f16(al, br[kk], accr, 0, 0, 0);
                accz = __builtin_amdgcn_mfma_f32_16x16x32_f16(ah, bz[kk], accz, 0, 0, 0);
                accz = __builtin_amdgcn_mfma_f32_16x16x32_f16(al, bz[kk], accz, 0, 0, 0);
                acchn = __builtin_amdgcn_mfma_f32_16x16x32_f16(ah, bn[kk], acchn, 0, 0, 0);
                acchn = __builtin_amdgcn_mfma_f32_16x16x32_f16(al, bn[kk], acchn, 0, 0, 0);
            }
#pragma unroll
            for (int kk = 16; kk < 20; ++kk) {
                f16x8 ah = *(const f16x8*)(arh + 512 + (kk - 16) * 32);
                f16x8 al = *(const f16x8*)(arl + 512 + (kk - 16) * 32);
                accr = __builtin_amdgcn_mfma_f32_16x16x32_f16(ah, br[kk], accr, 0, 0, 0);
                accr = __builtin_amdgcn_mfma_f32_16x16x32_f16(al, br[kk], accr, 0, 0, 0);
                accz = __builtin_amdgcn_mfma_f32_16x16x32_f16(ah, bz[kk], accz, 0, 0, 0);
                accz = __builtin_amdgcn_mfma_f32_16x16x32_f16(al, bz[kk], accz, 0, 0, 0);
                accxn = __builtin_amdgcn_mfma_f32_16x16x32_f16(ah, bn[kk], accxn, 0, 0, 0);
                accxn = __builtin_amdgcn_mfma_f32_16x16x32_f16(al, bn[kk], accxn, 0, 0, 0);
            }
            // (barrier B removed — WAR covered by barrier A of t+1; R18-proven)

            // ---- gates + state update + tagged h stores (fire-and-forget) ----
            unsigned* hwp = hbuf + ((size_t)((1 - par) * 2 + d) * B_ + b0) * H_;
            const unsigned tg = ((((unsigned)t) >> 1) & 1u) ^ 1u;
            float yv[4];
            int so4[4];
#pragma unroll
            for (int i = 0; i < 4; ++i) {
                int bl = quad * 4 + i;
                float r = sigm(accr[i] + bias_r);
                float zg = sigm(accz[i] + bias_z);
                float ng = tanhf_((accxn[i] + bihn) + r * (acchn[i] + bhhn));
                float hcand = (1.0f - zg) * ng + zg * h_own[i];
                bool m = (t < len4[i]);
                yv[i] = m ? hcand : 0.0f;
                h_own[i] = m ? hcand : h_own[i];
                _Float16 hhi = (_Float16)h_own[i];
                _Float16 hlo = (_Float16)(h_own[i] - (float)hhi);
                unsigned packed = (unsigned)f16bits(hhi) |
                                  ((((unsigned)f16bits(hlo) & 0xFFFEu) | tg) << 16);
                __hip_atomic_store(hwp + (size_t)bl * H_ + j0w + col, packed,
                                   __ATOMIC_RELAXED, __HIP_MEMORY_SCOPE_AGENT);
                so4[i] = (d && m) ? (len4[i] - 1 - t) : t;
            }
            // ---- Ycat stores: drain overlaps peers' polling ----
#pragma unroll
            for (int i = 0; i < 4; ++i) {
                int bl = quad * 4 + i;
                Ycat[((size_t)(b0 + bl) * S_ + so4[i]) * 1024 + d * 512 + j0w + col] =
                    (_Float16)yv[i];
            }
        } else {
            // whole group masked: zeros at s_out = t; no exchange traffic
#pragma unroll
            for (int i = 0; i < 4; ++i) {
                int bl = quad * 4 + i;
                Ycat[((size_t)(b0 + bl) * S_ + t) * 1024 + d * 512 + j0w + col] = (_Float16)0.0f;
            }
        }
    }
}

// ---------------------------------------------------------------------------
// Final linear as MFMA GEMM: out[pos,l] = blin[l] + sum_c Y[pos,c]*W[l,c].
// [16384 x 1024] x [1024 x 64]. Block = 256 thr (4 waves), covers 64 pos;
// wave covers 16 pos x 64 l (4 n-tiles). A-frags load directly from Ycat
// (f16x8, layout = verified GRU operand pattern); W as hi/lo f16 planes
// (exact fp32 reconstruction). 256 MFMA/wave; grid 256.
// ---------------------------------------------------------------------------
__launch_bounds__(256, 1)
__global__ void lin_kernel(const _Float16* __restrict__ Ycat,
                           const _Float16* __restrict__ Whi,
                           const _Float16* __restrict__ Wlo,
                           const float* __restrict__ blinF,
                           float* __restrict__ out) {
    const int tid = threadIdx.x;
    const int wave = tid >> 6;
    const int lane = tid & 63;
    const int quad = lane >> 4;
    const int col = lane & 15;
    const int pos0 = blockIdx.x * 64 + wave * 16;

    const _Float16* arow = Ycat + (size_t)(pos0 + col) * 1024 + quad * 8;

    f32x4 acc[4] = {{0.f, 0.f, 0.f, 0.f}, {0.f, 0.f, 0.f, 0.f},
                    {0.f, 0.f, 0.f, 0.f}, {0.f, 0.f, 0.f, 0.f}};
#pragma unroll 4
    for (int c = 0; c < 1024; c += 32) {
        f16x8 a = *(const f16x8*)(arow + c);
#pragma unroll
        for (int nt = 0; nt < 4; ++nt) {
            const size_t wo = (size_t)(nt * 16 + col) * 1024 + c + quad * 8;
            f16x8 bh = *(const f16x8*)(Whi + wo);
            f16x8 bl = *(const f16x8*)(Wlo + wo);
            acc[nt] = __builtin_amdgcn_mfma_f32_16x16x32_f16(a, bh, acc[nt], 0, 0, 0);
            acc[nt] = __builtin_amdgcn_mfma_f32_16x16x32_f16(a, bl, acc[nt], 0, 0, 0);
        }
    }
    // C layout: row = quad*4 + reg (pos), col = lane&15 (l within n-tile)
#pragma unroll
    for (int nt = 0; nt < 4; ++nt) {
        int l = nt * 16 + col;
        float bias = blinF[l];
#pragma unroll
        for (int r = 0; r < 4; ++r) {
            int pos = pos0 + quad * 4 + r;
            out[(size_t)pos * L_ + l] = acc[nt][r] + bias;
        }
    }
}

extern "C" void kernel_launch(void* const* d_in, const int* in_sizes, int n_in,
                              void* d_out, int out_size, void* d_ws, size_t ws_size,
                              hipStream_t stream) {
    const int* chars = (const int*)d_in[0];
    const int* lengths = (const int*)d_in[1];
    const void* forget = d_in[2];
    const void* Wihf = d_in[3];
    const void* Whhf = d_in[4];
    const void* bihf = d_in[5];
    const void* bhhf = d_in[6];
    const void* Wihb = d_in[7];
    const void* Whhb = d_in[8];
    const void* bihb = d_in[9];
    const void* bhhb = d_in[10];
    const void* Wlin = d_in[11];
    const void* blin = d_in[12];
    float* out = (float*)d_out;

    char* ws = (char*)d_ws;
    unsigned* hbuf = (unsigned*)(ws + 0);
    unsigned short* xhi = (unsigned short*)(ws + OFF_XHI);
    unsigned short* xlo = (unsigned short*)(ws + OFF_XLO);
    _Float16* whalf = (_Float16*)(ws + OFF_WH);
    float* smallF = (float*)(ws + OFF_SMALL);
    _Float16* Ycat = (_Float16*)(ws + OFF_YCAT);
    _Float16* wlh = (_Float16*)(ws + OFF_WLH);
    _Float16* wll = (_Float16*)(ws + OFF_WLL);

    // fused prep: whalf (7680) + small (281) + wlin planes (256) +
    // fofe (8192) + hbuf zeroing (1024) — no separate memset dispatch
    hipLaunchKernelGGL(prep_all, dim3(17433), dim3(256), 0, stream,
                       Whhf, Whhb, Wihf, Wihb, bihf, bhhf, bihb, bhhb,
                       Wlin, blin, forget, chars,
                       whalf, smallF, wlh, wll, xhi, xlo, hbuf);

    // 16 chains x 8 blocks x 256 threads; tagged fire-and-forget exchange.
    hipLaunchKernelGGL(gru_kernel, dim3(128), dim3(256), 0, stream,
                       lengths, whalf, smallF, xhi, xlo, hbuf, Ycat);

    // MFMA GEMM epilogue: 256 blocks x 64 pos.
    hipLaunchKernelGGL(lin_kernel, dim3(256), dim3(256), 0, stream,
                       Ycat, wlh, wll, smallF + 71680, out);
}

// Round 14
// 588.428 us; speedup vs baseline: 1.1364x; 1.1364x over previous
//
#include <hip/hip_runtime.h>
#include <hip/hip_bf16.h>

// Problem constants
#define B_ 128
#define S_ 128
#define W_ 16
#define V_ 128
#define H_ 512
#define L_ 64

typedef _Float16 f16x8 __attribute__((ext_vector_type(8)));
typedef float f32x4 __attribute__((ext_vector_type(4)));

__device__ __forceinline__ float sigm(float v) { return 1.0f / (1.0f + __expf(-v)); }
__device__ __forceinline__ float tanhf_(float v) { return 1.0f - 2.0f / (1.0f + __expf(2.0f * v)); }

__device__ __forceinline__ unsigned short f16bits(_Float16 h) {
    return __builtin_bit_cast(unsigned short, h);
}

// ---------------------------------------------------------------------------
// Workspace layout (bytes):
//   hbuf  u32 packed(hi,lo) [par2][dir2][128][512] @ 0        (1048576)
//   (dead slots/flag)                              @ 1048576
//   xhi   u16 [128][128][128]                      @ 1065024  (4194304)
//   xlo   u16 [128][128][128]                      @ 5259328  (4194304)
//   whalf f16 [1966080]                            @ 9453632  (3932160)
//         [whhf 786432 | whhb 786432 | wihf 196608 | wihb 196608]
//   smallF f32 [71745]                             @ 13385792 (287040)
//         [bihf 1536|bhhf 1536|bihb 1536|bhhb 1536|wlin 65536|blin 64|fg 1]
//   Ycat  f16 [128][128][1024]                     @ 13672832 (33554432)
//   wlinh f16 [64][1024]                           @ 47227264 (131072)
//   wlinl f16 [64][1024]                           @ 47358336 (131072) -> ends 47489408
// ---------------------------------------------------------------------------
#define OFF_XHI   1065024
#define OFF_XLO   5259328
#define OFF_WH    9453632
#define OFF_SMALL 13385792
#define OFF_YCAT  13672832
#define OFF_WLH   47227264
#define OFF_WLL   47358336

// ---------------------------------------------------------------------------
// R23 prep (= R21/R22 prep, kept): ALL prep + hbuf zeroing fused into ONE
// dispatch; dtype flag computed per-block (deterministic ballot vote over
// the same 256 words of Whhf).
//   bid <  7680           : whalf canonicalization (fp16 RTN)
//   bid <  7961           : biases/W_lin/b_lin/forget -> fp32
//   bid <  8217           : W_lin hi/lo f16 planes
//   bid < 16409           : FOFE -> xhi/xlo
//   else (1024 blocks)    : zero hbuf (tag bits = 0; visible to gru via
//                           kernel-boundary release->acquire)
// ---------------------------------------------------------------------------
__global__ void prep_all(const void* __restrict__ whhf, const void* __restrict__ whhb,
                         const void* __restrict__ wihf, const void* __restrict__ wihb,
                         const void* __restrict__ bihf, const void* __restrict__ bhhf,
                         const void* __restrict__ bihb, const void* __restrict__ bhhb,
                         const void* __restrict__ wlin, const void* __restrict__ blin,
                         const void* __restrict__ fgp, const int* __restrict__ chars,
                         _Float16* __restrict__ whalf, float* __restrict__ smallF,
                         _Float16* __restrict__ whi, _Float16* __restrict__ wlo,
                         unsigned short* __restrict__ xhi, unsigned short* __restrict__ xlo,
                         unsigned* __restrict__ hbuf) {
    const int bid = blockIdx.x;
    const int tid = threadIdx.x;
    const int wave = tid >> 6;
    const int lane = tid & 63;

    if (bid >= 16409) {  // hbuf zeroing: 1024 blocks x 1KB
        hbuf[(bid - 16409) * 256 + tid] = 0u;
        return;
    }

    // ---- per-block dtype vote (identical inputs -> identical result) ----
    __shared__ int wv[4];
    {
        unsigned word = ((const unsigned*)whhf)[tid];
        unsigned e = (word >> 7) & 0xFFu;
        unsigned long long m = __ballot(e >= 64u && e <= 126u);
        if (lane == 0) wv[wave] = __popcll(m);
    }
    __syncthreads();
    const int fl = (wv[0] + wv[1] + wv[2] + wv[3] >= 160) ? 1 : 0;  // 1 = bf16

    if (bid < 7680) {
        int i = bid * 256 + tid;  // 1966080 exactly
        const void* src;
        int off;
        if (i < 786432)       { src = whhf; off = i; }
        else if (i < 1572864) { src = whhb; off = i - 786432; }
        else if (i < 1769472) { src = wihf; off = i - 1572864; }
        else                  { src = wihb; off = i - 1769472; }
        float v = fl ? __bfloat162float(((const __hip_bfloat16*)src)[off])
                     : ((const float*)src)[off];
        whalf[i] = (_Float16)v;
    } else if (bid < 7961) {
        int i = (bid - 7680) * 256 + tid;
        if (i >= 71745) return;
        const void* src;
        int off;
        if (i < 1536)       { src = bihf; off = i; }
        else if (i < 3072)  { src = bhhf; off = i - 1536; }
        else if (i < 4608)  { src = bihb; off = i - 3072; }
        else if (i < 6144)  { src = bhhb; off = i - 4608; }
        else if (i < 71680) { src = wlin; off = i - 6144; }
        else if (i < 71744) { src = blin; off = i - 71680; }
        else                { src = fgp;  off = 0; }
        float v = fl ? __bfloat162float(((const __hip_bfloat16*)src)[off])
                     : ((const float*)src)[off];
        smallF[i] = v;
    } else if (bid < 8217) {
        int i = (bid - 7961) * 256 + tid;  // 65536
        float v = fl ? __bfloat162float(((const __hip_bfloat16*)wlin)[i])
                     : ((const float*)wlin)[i];
        _Float16 hi = (_Float16)v;
        whi[i] = hi;
        wlo[i] = (_Float16)(v - (float)hi);
    } else {
        // FOFE: 2 positions per block
        __shared__ int cS[2][W_];
        const int fb = bid - 8217;
        int sub = tid >> 7;
        int v = tid & 127;
        int bi = fb * 2 + sub;  // b*S + s
        if (v < W_) cS[sub][v] = chars[bi * W_ + v];
        __syncthreads();
        float f = fl ? __bfloat162float(*(const __hip_bfloat16*)fgp)
                     : *(const float*)fgp;
        float wt[W_];
        float cur = 1.0f;
#pragma unroll
        for (int w = W_ - 1; w >= 0; --w) {
            bool m = (cS[sub][w] != 0);
            wt[w] = m ? cur : 0.0f;
            if (m) cur *= f;
        }
        float acc = 0.0f;
#pragma unroll
        for (int w = 0; w < W_; ++w) acc += (cS[sub][w] == v) ? wt[w] : 0.0f;
        _Float16 hi = (_Float16)acc;
        _Float16 lo = (_Float16)(acc - (float)hi);
        xhi[(size_t)bi * V_ + v] = f16bits(hi);
        xlo[(size_t)bi * V_ + v] = f16bits(lo);
    }
}

// ---------------------------------------------------------------------------
// Persistent bidirectional GRU.
// R23 = R18 gru BYTE-EXACT (the 478us champion). R22's sole gru diff — the
// hoisted-issue volley — is reverted to R18's load-then-validate loop.
// Evidence: R18 (load-then-validate) 478, R20 489 vs R19/R21/R22 (hoisted
// issue variants) 547/545/560; VGPR 188 vs 192 confirms codegen divergence.
// This round discriminates volley-shape vs cross-container noise:
//   gru ~480 & VGPR 188  -> volley shape was the regression; champion back.
//   gru ~555             -> spread is environmental; floor confirmed.
// Exchange protocol (proven R16/R18): tagged fire-and-forget, lo-plane LSB
// tag(t)=((t>>1)&1)^1, relaxed agent atomics, LDS double-buffer, single
// barrier per step.
// ---------------------------------------------------------------------------
__launch_bounds__(256, 1)
__global__ void gru_kernel(const int* __restrict__ lengths,
                           const _Float16* __restrict__ wh,
                           const float* __restrict__ biasF,
                           const unsigned short* __restrict__ xhi,
                           const unsigned short* __restrict__ xlo,
                           unsigned* __restrict__ hbuf,
                           _Float16* __restrict__ Ycat) {
    constexpr int RSTR = 656;  // 640 + 16 pad halves (0 conflicts measured r5/r7)
    __shared__ _Float16 Ahi[2][16 * RSTR];
    __shared__ _Float16 Alo[2][16 * RSTR];
    __shared__ int lenS[16];

    const int tid = threadIdx.x;
    const int chain = blockIdx.x & 15;
    const int blk = blockIdx.x >> 4;    // 0..7
    const int d = chain & 1;
    const int bg = chain >> 1;
    const int b0 = bg * 16;
    const int wave = tid >> 6;          // 0..3
    const int lane = tid & 63;
    const int quad = lane >> 4;
    const int col = lane & 15;
    const int j0w = (blk * 4 + wave) * 16;  // 0..496

    const _Float16* Whh = wh + (d ? 786432 : 0);
    const _Float16* Wih = wh + 1572864 + (d ? 196608 : 0);
    const float* bih = biasF + (d ? 3072 : 0);
    const float* bhh = biasF + 1536 + (d ? 3072 : 0);

    if (tid < 16) lenS[tid] = lengths[b0 + tid];
    __syncthreads();

    const int g_r = j0w + col;  // r row; z = 512+g_r; n = 1024+g_r

    // Persistent B fragments: lane holds W[g][kk*32 + quad*8 + 0..7]
    f16x8 br[20], bz[20], bn[20];
#pragma unroll
    for (int kk = 0; kk < 16; ++kk) {
        int k = kk * 32 + quad * 8;
        br[kk] = *(const f16x8*)(Whh + (size_t)(g_r)*H_ + k);
        bz[kk] = *(const f16x8*)(Whh + (size_t)(512 + g_r) * H_ + k);
        bn[kk] = *(const f16x8*)(Whh + (size_t)(1024 + g_r) * H_ + k);
    }
#pragma unroll
    for (int kk = 16; kk < 20; ++kk) {
        int k = (kk - 16) * 32 + quad * 8;
        br[kk] = *(const f16x8*)(Wih + (size_t)(g_r)*V_ + k);
        bz[kk] = *(const f16x8*)(Wih + (size_t)(512 + g_r) * V_ + k);
        bn[kk] = *(const f16x8*)(Wih + (size_t)(1024 + g_r) * V_ + k);
    }

    const float bias_r = bih[g_r] + bhh[g_r];
    const float bias_z = bih[512 + g_r] + bhh[512 + g_r];
    const float bihn = bih[1024 + g_r];
    const float bhhn = bhh[1024 + g_r];

    int len4[4];
#pragma unroll
    for (int i = 0; i < 4; ++i) len4[i] = lenS[quad * 4 + i];
    const int maxlen = lenS[0];  // lengths sorted descending

    float h_own[4] = {0.f, 0.f, 0.f, 0.f};  // fp32 master state (b=quad*4+i, j=col)

    // x staging: 16 rows x 16 chunks of 8 halves (int4 per plane per thread)
    const int xb = tid >> 4;
    const int xv8 = (tid & 15) * 8;

    const unsigned long long tagMsk = (1ULL << 16) | (1ULL << 48);

    for (int t = 0; t < S_; ++t) {
        if (t < maxlen) {
            const int par = t & 1;
            const _Float16* arh = &Ahi[par][col * RSTR + quad * 8];
            const _Float16* arl = &Alo[par][col * RSTR + quad * 8];
            // ---- x loads (plain cached, RO; issued first, overlap volley) ----
            int lxb = lenS[xb];
            int sxb = d ? max(0, lxb - 1 - t) : t;
            int4 xh4 = *(const int4*)(xhi + ((size_t)(b0 + xb) * S_ + sxb) * V_ + xv8);
            int4 xl4 = *(const int4*)(xlo + ((size_t)(b0 + xb) * S_ + sxb) * V_ + xv8);

            // ---- h gather: tag-validated volley of relaxed agent u64 loads.
            //      Row i = batch i, col-pair (2*tid, 2*tid+1). R18-exact
            //      load-then-validate loop. ----
            unsigned* hrp = hbuf + ((size_t)(par * 2 + d) * B_ + b0) * H_;
            unsigned long long hv[16];
            if (t > 0) {
                const unsigned te = ((((unsigned)(t - 1)) >> 1) & 1u) ^ 1u;
                const unsigned long long tagPat =
                    ((unsigned long long)te << 16) | ((unsigned long long)te << 48);
                unsigned pend = 0xFFFFu;
                unsigned round = 0;
                while (true) {
#pragma unroll
                    for (int i = 0; i < 16; ++i)
                        if (pend & (1u << i))
                            hv[i] = __hip_atomic_load(
                                (const unsigned long long*)(hrp + (size_t)i * H_ + tid * 2),
                                __ATOMIC_RELAXED, __HIP_MEMORY_SCOPE_AGENT);
                    unsigned np = 0;
#pragma unroll
                    for (int i = 0; i < 16; ++i)
                        if ((pend & (1u << i)) && (hv[i] & tagMsk) != tagPat) np |= (1u << i);
                    pend = np;
                    if (!pend) break;
                    ++round;
                    if (round > 4u) __builtin_amdgcn_s_sleep(1);
                    if ((round & 31u) == 31u)  // stale-L2 insurance; free if unused
                        __builtin_amdgcn_fence(__ATOMIC_ACQUIRE, "agent");
                    if (round > 400000u) break;  // malfunction -> visible failure
                }
            } else {
                // t=0: initial h is all zeros — no loads needed
#pragma unroll
                for (int i = 0; i < 16; ++i) hv[i] = 0ULL;
            }

            // ---- stage x into LDS[par] ----
            *(int4*)&Ahi[par][xb * RSTR + 512 + xv8] = xh4;
            *(int4*)&Alo[par][xb * RSTR + 512 + xv8] = xl4;
            // ---- unpack h (clear tag bits) and stage into LDS[par] ----
#pragma unroll
            for (int i = 0; i < 16; ++i) {
                unsigned p0 = (unsigned)hv[i];
                unsigned p1 = (unsigned)(hv[i] >> 32);
                unsigned hi2 = (p0 & 0xffffu) | (p1 << 16);
                unsigned lo2 = ((p0 >> 16) | (p1 & 0xffff0000u)) & ~0x00010001u;
                *(unsigned*)&Ahi[par][i * RSTR + tid * 2] = hi2;
                *(unsigned*)&Alo[par][i * RSTR + tid * 2] = lo2;
            }
            __syncthreads();  // A: staging complete (only barrier per step)

            // ---- MFMA: hw = (h_hi + h_lo) @ W^T (fp16 in, fp32 acc) ----
            f32x4 accr = {0.f, 0.f, 0.f, 0.f};
            f32x4 accz = {0.f, 0.f, 0.f, 0.f};
            f32x4 acchn = {0.f, 0.f, 0.f, 0.f};
            f32x4 accxn = {0.f, 0.f, 0.f, 0.f};
#pragma unroll
            for (int kk = 0; kk < 16; ++kk) {
                f16x8 ah = *(const f16x8*)(arh + kk * 32);
                f16x8 al = *(const f16x8*)(arl + kk * 32);
                accr = __builtin_amdgcn_mfma_f32_16x16x32_f16(ah, br[kk], accr, 0, 0, 0);
                accr = __builtin_amdgcn_mfma_f32_16x16x32_f16(al, br[kk], accr, 0, 0, 0);
                accz = __builtin_amdgcn_mfma_f32_16x16x32_f16(ah, bz[kk], accz, 0, 0, 0);
                accz = __builtin_amdgcn_mfma_f32_16x16x32_f16(al, bz[kk], accz, 0, 0, 0);
                acchn = __builtin_amdgcn_mfma_f32_16x16x32_f16(ah, bn[kk], acchn, 0, 0, 0);
                acchn = __builtin_amdgcn_mfma_f32_16x16x32_f16(al, bn[kk], acchn, 0, 0, 0);
            }
#pragma unroll
            for (int kk = 16; kk < 20; ++kk) {
                f16x8 ah = *(const f16x8*)(arh + 512 + (kk - 16) * 32);
                f16x8 al = *(const f16x8*)(arl + 512 + (kk - 16) * 32);
                accr = __builtin_amdgcn_mfma_f32_16x16x32_f16(ah, br[kk], accr, 0, 0, 0);
                accr = __builtin_amdgcn_mfma_f32_16x16x32_f16(al, br[kk], accr, 0, 0, 0);
                accz = __builtin_amdgcn_mfma_f32_16x16x32_f16(ah, bz[kk], accz, 0, 0, 0);
                accz = __builtin_amdgcn_mfma_f32_16x16x32_f16(al, bz[kk], accz, 0, 0, 0);
                accxn = __builtin_amdgcn_mfma_f32_16x16x32_f16(ah, bn[kk], accxn, 0, 0, 0);
                accxn = __builtin_amdgcn_mfma_f32_16x16x32_f16(al, bn[kk], accxn, 0, 0, 0);
            }
            // (barrier B removed — WAR covered by barrier A of t+1; R18-proven)

            // ---- gates + state update + tagged h stores (fire-and-forget) ----
            unsigned* hwp = hbuf + ((size_t)((1 - par) * 2 + d) * B_ + b0) * H_;
            const unsigned tg = ((((unsigned)t) >> 1) & 1u) ^ 1u;
            float yv[4];
            int so4[4];
#pragma unroll
            for (int i = 0; i < 4; ++i) {
                int bl = quad * 4 + i;
                float r = sigm(accr[i] + bias_r);
                float zg = sigm(accz[i] + bias_z);
                float ng = tanhf_((accxn[i] + bihn) + r * (acchn[i] + bhhn));
                float hcand = (1.0f - zg) * ng + zg * h_own[i];
                bool m = (t < len4[i]);
                yv[i] = m ? hcand : 0.0f;
                h_own[i] = m ? hcand : h_own[i];
                _Float16 hhi = (_Float16)h_own[i];
                _Float16 hlo = (_Float16)(h_own[i] - (float)hhi);
                unsigned packed = (unsigned)f16bits(hhi) |
                                  ((((unsigned)f16bits(hlo) & 0xFFFEu) | tg) << 16);
                __hip_atomic_store(hwp + (size_t)bl * H_ + j0w + col, packed,
                                   __ATOMIC_RELAXED, __HIP_MEMORY_SCOPE_AGENT);
                so4[i] = (d && m) ? (len4[i] - 1 - t) : t;
            }
            // ---- Ycat stores: drain overlaps peers' polling ----
#pragma unroll
            for (int i = 0; i < 4; ++i) {
                int bl = quad * 4 + i;
                Ycat[((size_t)(b0 + bl) * S_ + so4[i]) * 1024 + d * 512 + j0w + col] =
                    (_Float16)yv[i];
            }
        } else {
            // whole group masked: zeros at s_out = t; no exchange traffic
#pragma unroll
            for (int i = 0; i < 4; ++i) {
                int bl = quad * 4 + i;
                Ycat[((size_t)(b0 + bl) * S_ + t) * 1024 + d * 512 + j0w + col] = (_Float16)0.0f;
            }
        }
    }
}

// ---------------------------------------------------------------------------
// Final linear as MFMA GEMM: out[pos,l] = blin[l] + sum_c Y[pos,c]*W[l,c].
// [16384 x 1024] x [1024 x 64]. Block = 256 thr (4 waves), covers 64 pos;
// wave covers 16 pos x 64 l (4 n-tiles). A-frags load directly from Ycat
// (f16x8, layout = verified GRU operand pattern); W as hi/lo f16 planes
// (exact fp32 reconstruction). 256 MFMA/wave; grid 256.
// ---------------------------------------------------------------------------
__launch_bounds__(256, 1)
__global__ void lin_kernel(const _Float16* __restrict__ Ycat,
                           const _Float16* __restrict__ Whi,
                           const _Float16* __restrict__ Wlo,
                           const float* __restrict__ blinF,
                           float* __restrict__ out) {
    const int tid = threadIdx.x;
    const int wave = tid >> 6;
    const int lane = tid & 63;
    const int quad = lane >> 4;
    const int col = lane & 15;
    const int pos0 = blockIdx.x * 64 + wave * 16;

    const _Float16* arow = Ycat + (size_t)(pos0 + col) * 1024 + quad * 8;

    f32x4 acc[4] = {{0.f, 0.f, 0.f, 0.f}, {0.f, 0.f, 0.f, 0.f},
                    {0.f, 0.f, 0.f, 0.f}, {0.f, 0.f, 0.f, 0.f}};
#pragma unroll 4
    for (int c = 0; c < 1024; c += 32) {
        f16x8 a = *(const f16x8*)(arow + c);
#pragma unroll
        for (int nt = 0; nt < 4; ++nt) {
            const size_t wo = (size_t)(nt * 16 + col) * 1024 + c + quad * 8;
            f16x8 bh = *(const f16x8*)(Whi + wo);
            f16x8 bl = *(const f16x8*)(Wlo + wo);
            acc[nt] = __builtin_amdgcn_mfma_f32_16x16x32_f16(a, bh, acc[nt], 0, 0, 0);
            acc[nt] = __builtin_amdgcn_mfma_f32_16x16x32_f16(a, bl, acc[nt], 0, 0, 0);
        }
    }
    // C layout: row = quad*4 + reg (pos), col = lane&15 (l within n-tile)
#pragma unroll
    for (int nt = 0; nt < 4; ++nt) {
        int l = nt * 16 + col;
        float bias = blinF[l];
#pragma unroll
        for (int r = 0; r < 4; ++r) {
            int pos = pos0 + quad * 4 + r;
            out[(size_t)pos * L_ + l] = acc[nt][r] + bias;
        }
    }
}

extern "C" void kernel_launch(void* const* d_in, const int* in_sizes, int n_in,
                              void* d_out, int out_size, void* d_ws, size_t ws_size,
                              hipStream_t stream) {
    const int* chars = (const int*)d_in[0];
    const int* lengths = (const int*)d_in[1];
    const void* forget = d_in[2];
    const void* Wihf = d_in[3];
    const void* Whhf = d_in[4];
    const void* bihf = d_in[5];
    const void* bhhf = d_in[6];
    const void* Wihb = d_in[7];
    const void* Whhb = d_in[8];
    const void* bihb = d_in[9];
    const void* bhhb = d_in[10];
    const void* Wlin = d_in[11];
    const void* blin = d_in[12];
    float* out = (float*)d_out;

    char* ws = (char*)d_ws;
    unsigned* hbuf = (unsigned*)(ws + 0);
    unsigned short* xhi = (unsigned short*)(ws + OFF_XHI);
    unsigned short* xlo = (unsigned short*)(ws + OFF_XLO);
    _Float16* whalf = (_Float16*)(ws + OFF_WH);
    float* smallF = (float*)(ws + OFF_SMALL);
    _Float16* Ycat = (_Float16*)(ws + OFF_YCAT);
    _Float16* wlh = (_Float16*)(ws + OFF_WLH);
    _Float16* wll = (_Float16*)(ws + OFF_WLL);

    // fused prep: whalf (7680) + small (281) + wlin planes (256) +
    // fofe (8192) + hbuf zeroing (1024) — no separate memset dispatch
    hipLaunchKernelGGL(prep_all, dim3(17433), dim3(256), 0, stream,
                       Whhf, Whhb, Wihf, Wihb, bihf, bhhf, bihb, bhhb,
                       Wlin, blin, forget, chars,
                       whalf, smallF, wlh, wll, xhi, xlo, hbuf);

    // 16 chains x 8 blocks x 256 threads; tagged fire-and-forget exchange.
    hipLaunchKernelGGL(gru_kernel, dim3(128), dim3(256), 0, stream,
                       lengths, whalf, smallF, xhi, xlo, hbuf, Ycat);

    // MFMA GEMM epilogue: 256 blocks x 64 pos.
    hipLaunchKernelGGL(lin_kernel, dim3(256), dim3(256), 0, stream,
                       Ycat, wlh, wll, smallF + 71680, out);
}

// Round 15
// 586.712 us; speedup vs baseline: 1.1397x; 1.0029x over previous
//
#include <hip/hip_runtime.h>
#include <hip/hip_bf16.h>

// Problem constants
#define B_ 128
#define S_ 128
#define W_ 16
#define V_ 128
#define H_ 512
#define L_ 64

typedef _Float16 f16x8 __attribute__((ext_vector_type(8)));
typedef float f32x4 __attribute__((ext_vector_type(4)));

__device__ __forceinline__ float sigm(float v) { return 1.0f / (1.0f + __expf(-v)); }
__device__ __forceinline__ float tanhf_(float v) { return 1.0f - 2.0f / (1.0f + __expf(2.0f * v)); }

__device__ __forceinline__ unsigned short f16bits(_Float16 h) {
    return __builtin_bit_cast(unsigned short, h);
}

__device__ __forceinline__ float bf16_to_f32(unsigned short u) {
    return __builtin_bit_cast(float, (unsigned)u << 16);
}

// ---------------------------------------------------------------------------
// Workspace layout (bytes):
//   hbuf  u32 packed(hi,lo) [par2][dir2][128][512] @ 0        (1048576)
//   (dead slots/flag)                              @ 1048576
//   xhi   u16 [128][128][128]                      @ 1065024  (4194304)
//   xlo   u16 [128][128][128]                      @ 5259328  (4194304)
//   whalf f16 [1966080]                            @ 9453632  (3932160)
//         [whhf 786432 | whhb 786432 | wihf 196608 | wihb 196608]
//   smallF f32 [71745]                             @ 13385792 (287040)
//         [bihf 1536|bhhf 1536|bihb 1536|bhhb 1536|wlin 65536|blin 64|fg 1]
//   Ycat  f16 [128][128][1024]                     @ 13672832 (33554432)
//   wlinh f16 [64][1024]                           @ 47227264 (131072)
//   wlinl f16 [64][1024]                           @ 47358336 (131072) -> ends 47489408
// ---------------------------------------------------------------------------
#define OFF_XHI   1065024
#define OFF_XLO   5259328
#define OFF_WH    9453632
#define OFF_SMALL 13385792
#define OFF_YCAT  13672832
#define OFF_WLH   47227264
#define OFF_WLL   47358336

// ---------------------------------------------------------------------------
// R24 prep: vectorized 4-wide where layout permits (Common-mistake #2 fix:
// hipcc does not auto-vectorize scalar bf16/f32 loads). Grid 17433 -> 10713.
//   bid <  1920           : whalf canonicalization, 4 elems/thread
//   bid <  2201           : biases/W_lin/b_lin/forget -> fp32 (scalar, 71745)
//   bid <  2265           : W_lin hi/lo f16 planes, 4 elems/thread
//   bid < 10457           : FOFE -> xhi/xlo (unchanged)
//   else (256 blocks)     : zero hbuf via int4 (tag bits = 0; visible to gru
//                           via kernel-boundary release->acquire)
// dtype flag computed per-block (deterministic ballot vote over the same
// 256 words of Whhf). bf16->f32 by bit-shift (exact); f32->f16 RTN by cast.
// ---------------------------------------------------------------------------
__global__ void prep_all(const void* __restrict__ whhf, const void* __restrict__ whhb,
                         const void* __restrict__ wihf, const void* __restrict__ wihb,
                         const void* __restrict__ bihf, const void* __restrict__ bhhf,
                         const void* __restrict__ bihb, const void* __restrict__ bhhb,
                         const void* __restrict__ wlin, const void* __restrict__ blin,
                         const void* __restrict__ fgp, const int* __restrict__ chars,
                         _Float16* __restrict__ whalf, float* __restrict__ smallF,
                         _Float16* __restrict__ whi, _Float16* __restrict__ wlo,
                         unsigned short* __restrict__ xhi, unsigned short* __restrict__ xlo,
                         unsigned* __restrict__ hbuf) {
    const int bid = blockIdx.x;
    const int tid = threadIdx.x;
    const int wave = tid >> 6;
    const int lane = tid & 63;

    if (bid >= 10457) {  // hbuf zeroing: 256 blocks x int4
        int4 z = {0, 0, 0, 0};
        ((int4*)hbuf)[(size_t)(bid - 10457) * 256 + tid] = z;
        return;
    }

    // ---- per-block dtype vote (identical inputs -> identical result) ----
    __shared__ int wv[4];
    {
        unsigned word = ((const unsigned*)whhf)[tid];
        unsigned e = (word >> 7) & 0xFFu;
        unsigned long long m = __ballot(e >= 64u && e <= 126u);
        if (lane == 0) wv[wave] = __popcll(m);
    }
    __syncthreads();
    const int fl = (wv[0] + wv[1] + wv[2] + wv[3] >= 160) ? 1 : 0;  // 1 = bf16

    if (bid < 1920) {
        // whalf: 4 elements per thread (region boundaries all %4 == 0)
        int i4 = (bid * 256 + tid) * 4;  // 0..1966076
        const void* src;
        int off;
        if (i4 < 786432)       { src = whhf; off = i4; }
        else if (i4 < 1572864) { src = whhb; off = i4 - 786432; }
        else if (i4 < 1769472) { src = wihf; off = i4 - 1572864; }
        else                   { src = wihb; off = i4 - 1769472; }
        float v[4];
        if (fl) {
            ushort4 s = *(const ushort4*)((const unsigned short*)src + off);
            v[0] = bf16_to_f32(s.x); v[1] = bf16_to_f32(s.y);
            v[2] = bf16_to_f32(s.z); v[3] = bf16_to_f32(s.w);
        } else {
            float4 s = *(const float4*)((const float*)src + off);
            v[0] = s.x; v[1] = s.y; v[2] = s.z; v[3] = s.w;
        }
        unsigned long long pk =
            (unsigned long long)f16bits((_Float16)v[0]) |
            ((unsigned long long)f16bits((_Float16)v[1]) << 16) |
            ((unsigned long long)f16bits((_Float16)v[2]) << 32) |
            ((unsigned long long)f16bits((_Float16)v[3]) << 48);
        *(unsigned long long*)(whalf + i4) = pk;
    } else if (bid < 2201) {
        int i = (bid - 1920) * 256 + tid;
        if (i >= 71745) return;
        const void* src;
        int off;
        if (i < 1536)       { src = bihf; off = i; }
        else if (i < 3072)  { src = bhhf; off = i - 1536; }
        else if (i < 4608)  { src = bihb; off = i - 3072; }
        else if (i < 6144)  { src = bhhb; off = i - 4608; }
        else if (i < 71680) { src = wlin; off = i - 6144; }
        else if (i < 71744) { src = blin; off = i - 71680; }
        else                { src = fgp;  off = 0; }
        float v = fl ? bf16_to_f32(((const unsigned short*)src)[off])
                     : ((const float*)src)[off];
        smallF[i] = v;
    } else if (bid < 2265) {
        // W_lin hi/lo planes: 4 elements per thread (65536 total)
        int i4 = ((bid - 2201) * 256 + tid) * 4;
        float v[4];
        if (fl) {
            ushort4 s = *(const ushort4*)((const unsigned short*)wlin + i4);
            v[0] = bf16_to_f32(s.x); v[1] = bf16_to_f32(s.y);
            v[2] = bf16_to_f32(s.z); v[3] = bf16_to_f32(s.w);
        } else {
            float4 s = *(const float4*)((const float*)wlin + i4);
            v[0] = s.x; v[1] = s.y; v[2] = s.z; v[3] = s.w;
        }
        unsigned long long ph = 0, pl = 0;
#pragma unroll
        for (int k = 0; k < 4; ++k) {
            _Float16 hi = (_Float16)v[k];
            _Float16 lo = (_Float16)(v[k] - (float)hi);
            ph |= (unsigned long long)f16bits(hi) << (16 * k);
            pl |= (unsigned long long)f16bits(lo) << (16 * k);
        }
        *(unsigned long long*)(whi + i4) = ph;
        *(unsigned long long*)(wlo + i4) = pl;
    } else {
        // FOFE: 2 positions per block (unchanged)
        __shared__ int cS[2][W_];
        const int fb = bid - 2265;
        int sub = tid >> 7;
        int v = tid & 127;
        int bi = fb * 2 + sub;  // b*S + s
        if (v < W_) cS[sub][v] = chars[bi * W_ + v];
        __syncthreads();
        float f = fl ? bf16_to_f32(*(const unsigned short*)fgp)
                     : *(const float*)fgp;
        float wt[W_];
        float cur = 1.0f;
#pragma unroll
        for (int w = W_ - 1; w >= 0; --w) {
            bool m = (cS[sub][w] != 0);
            wt[w] = m ? cur : 0.0f;
            if (m) cur *= f;
        }
        float acc = 0.0f;
#pragma unroll
        for (int w = 0; w < W_; ++w) acc += (cS[sub][w] == v) ? wt[w] : 0.0f;
        _Float16 hi = (_Float16)acc;
        _Float16 lo = (_Float16)(acc - (float)hi);
        xhi[(size_t)bi * V_ + v] = f16bits(hi);
        xlo[(size_t)bi * V_ + v] = f16bits(lo);
    }
}

// ---------------------------------------------------------------------------
// Persistent bidirectional GRU.
// R24 gru = R23/R18 BYTE-EXACT (478us champion, triple-confirmed):
//   - Tagged fire-and-forget exchange: h word donates lo-plane LSB (bit16)
//     as step tag, tag(t)=((t>>1)&1)^1. Producer: tagged relaxed-agent
//     atomic stores right after gates. Consumer: load-then-validate volley
//     loop (codegen-sensitive: hoisted-issue variants cost +70us).
//   - Same-step coalesced x staging; LDS double-buffer; single barrier/step.
// Floor evidence: R19 x-scatter -69us, R20 x-prefetch -11us, R21 half-volley
// -67us, R22 hoisted-volley -82us; R23 revert restored 478 exactly.
// ---------------------------------------------------------------------------
__launch_bounds__(256, 1)
__global__ void gru_kernel(const int* __restrict__ lengths,
                           const _Float16* __restrict__ wh,
                           const float* __restrict__ biasF,
                           const unsigned short* __restrict__ xhi,
                           const unsigned short* __restrict__ xlo,
                           unsigned* __restrict__ hbuf,
                           _Float16* __restrict__ Ycat) {
    constexpr int RSTR = 656;  // 640 + 16 pad halves (0 conflicts measured r5/r7)
    __shared__ _Float16 Ahi[2][16 * RSTR];
    __shared__ _Float16 Alo[2][16 * RSTR];
    __shared__ int lenS[16];

    const int tid = threadIdx.x;
    const int chain = blockIdx.x & 15;
    const int blk = blockIdx.x >> 4;    // 0..7
    const int d = chain & 1;
    const int bg = chain >> 1;
    const int b0 = bg * 16;
    const int wave = tid >> 6;          // 0..3
    const int lane = tid & 63;
    const int quad = lane >> 4;
    const int col = lane & 15;
    const int j0w = (blk * 4 + wave) * 16;  // 0..496

    const _Float16* Whh = wh + (d ? 786432 : 0);
    const _Float16* Wih = wh + 1572864 + (d ? 196608 : 0);
    const float* bih = biasF + (d ? 3072 : 0);
    const float* bhh = biasF + 1536 + (d ? 3072 : 0);

    if (tid < 16) lenS[tid] = lengths[b0 + tid];
    __syncthreads();

    const int g_r = j0w + col;  // r row; z = 512+g_r; n = 1024+g_r

    // Persistent B fragments: lane holds W[g][kk*32 + quad*8 + 0..7]
    f16x8 br[20], bz[20], bn[20];
#pragma unroll
    for (int kk = 0; kk < 16; ++kk) {
        int k = kk * 32 + quad * 8;
        br[kk] = *(const f16x8*)(Whh + (size_t)(g_r)*H_ + k);
        bz[kk] = *(const f16x8*)(Whh + (size_t)(512 + g_r) * H_ + k);
        bn[kk] = *(const f16x8*)(Whh + (size_t)(1024 + g_r) * H_ + k);
    }
#pragma unroll
    for (int kk = 16; kk < 20; ++kk) {
        int k = (kk - 16) * 32 + quad * 8;
        br[kk] = *(const f16x8*)(Wih + (size_t)(g_r)*V_ + k);
        bz[kk] = *(const f16x8*)(Wih + (size_t)(512 + g_r) * V_ + k);
        bn[kk] = *(const f16x8*)(Wih + (size_t)(1024 + g_r) * V_ + k);
    }

    const float bias_r = bih[g_r] + bhh[g_r];
    const float bias_z = bih[512 + g_r] + bhh[512 + g_r];
    const float bihn = bih[1024 + g_r];
    const float bhhn = bhh[1024 + g_r];

    int len4[4];
#pragma unroll
    for (int i = 0; i < 4; ++i) len4[i] = lenS[quad * 4 + i];
    const int maxlen = lenS[0];  // lengths sorted descending

    float h_own[4] = {0.f, 0.f, 0.f, 0.f};  // fp32 master state (b=quad*4+i, j=col)

    // x staging: 16 rows x 16 chunks of 8 halves (int4 per plane per thread)
    const int xb = tid >> 4;
    const int xv8 = (tid & 15) * 8;

    const unsigned long long tagMsk = (1ULL << 16) | (1ULL << 48);

    for (int t = 0; t < S_; ++t) {
        if (t < maxlen) {
            const int par = t & 1;
            const _Float16* arh = &Ahi[par][col * RSTR + quad * 8];
            const _Float16* arl = &Alo[par][col * RSTR + quad * 8];
            // ---- x loads (plain cached, RO; issued first, overlap volley) ----
            int lxb = lenS[xb];
            int sxb = d ? max(0, lxb - 1 - t) : t;
            int4 xh4 = *(const int4*)(xhi + ((size_t)(b0 + xb) * S_ + sxb) * V_ + xv8);
            int4 xl4 = *(const int4*)(xlo + ((size_t)(b0 + xb) * S_ + sxb) * V_ + xv8);

            // ---- h gather: tag-validated volley of relaxed agent u64 loads.
            //      Row i = batch i, col-pair (2*tid, 2*tid+1). R18-exact
            //      load-then-validate loop. ----
            unsigned* hrp = hbuf + ((size_t)(par * 2 + d) * B_ + b0) * H_;
            unsigned long long hv[16];
            if (t > 0) {
                const unsigned te = ((((unsigned)(t - 1)) >> 1) & 1u) ^ 1u;
                const unsigned long long tagPat =
                    ((unsigned long long)te << 16) | ((unsigned long long)te << 48);
                unsigned pend = 0xFFFFu;
                unsigned round = 0;
                while (true) {
#pragma unroll
                    for (int i = 0; i < 16; ++i)
                        if (pend & (1u << i))
                            hv[i] = __hip_atomic_load(
                                (const unsigned long long*)(hrp + (size_t)i * H_ + tid * 2),
                                __ATOMIC_RELAXED, __HIP_MEMORY_SCOPE_AGENT);
                    unsigned np = 0;
#pragma unroll
                    for (int i = 0; i < 16; ++i)
                        if ((pend & (1u << i)) && (hv[i] & tagMsk) != tagPat) np |= (1u << i);
                    pend = np;
                    if (!pend) break;
                    ++round;
                    if (round > 4u) __builtin_amdgcn_s_sleep(1);
                    if ((round & 31u) == 31u)  // stale-L2 insurance; free if unused
                        __builtin_amdgcn_fence(__ATOMIC_ACQUIRE, "agent");
                    if (round > 400000u) break;  // malfunction -> visible failure
                }
            } else {
                // t=0: initial h is all zeros — no loads needed
#pragma unroll
                for (int i = 0; i < 16; ++i) hv[i] = 0ULL;
            }

            // ---- stage x into LDS[par] ----
            *(int4*)&Ahi[par][xb * RSTR + 512 + xv8] = xh4;
            *(int4*)&Alo[par][xb * RSTR + 512 + xv8] = xl4;
            // ---- unpack h (clear tag bits) and stage into LDS[par] ----
#pragma unroll
            for (int i = 0; i < 16; ++i) {
                unsigned p0 = (unsigned)hv[i];
                unsigned p1 = (unsigned)(hv[i] >> 32);
                unsigned hi2 = (p0 & 0xffffu) | (p1 << 16);
                unsigned lo2 = ((p0 >> 16) | (p1 & 0xffff0000u)) & ~0x00010001u;
                *(unsigned*)&Ahi[par][i * RSTR + tid * 2] = hi2;
                *(unsigned*)&Alo[par][i * RSTR + tid * 2] = lo2;
            }
            __syncthreads();  // A: staging complete (only barrier per step)

            // ---- MFMA: hw = (h_hi + h_lo) @ W^T (fp16 in, fp32 acc) ----
            f32x4 accr = {0.f, 0.f, 0.f, 0.f};
            f32x4 accz = {0.f, 0.f, 0.f, 0.f};
            f32x4 acchn = {0.f, 0.f, 0.f, 0.f};
            f32x4 accxn = {0.f, 0.f, 0.f, 0.f};
#pragma unroll
            for (int kk = 0; kk < 16; ++kk) {
                f16x8 ah = *(const f16x8*)(arh + kk * 32);
                f16x8 al = *(const f16x8*)(arl + kk * 32);
                accr = __builtin_amdgcn_mfma_f32_16x16x32_f16(ah, br[kk], accr, 0, 0, 0);
                accr = __builtin_amdgcn_mfma_f32_16x16x32_f16(al, br[kk], accr, 0, 0, 0);
                accz = __builtin_amdgcn_mfma_f32_16x16x32_f16(ah, bz[kk], accz, 0, 0, 0);
                accz = __builtin_amdgcn_mfma_f32_16x16x32_f16(al, bz[kk], accz, 0, 0, 0);
                acchn = __builtin_amdgcn_mfma_f32_16x16x32_f16(ah, bn[kk], acchn, 0, 0, 0);
                acchn = __builtin_amdgcn_mfma_f32_16x16x32_f16(al, bn[kk], acchn, 0, 0, 0);
            }
#pragma unroll
            for (int kk = 16; kk < 20; ++kk) {
                f16x8 ah = *(const f16x8*)(arh + 512 + (kk - 16) * 32);
                f16x8 al = *(const f16x8*)(arl + 512 + (kk - 16) * 32);
                accr = __builtin_amdgcn_mfma_f32_16x16x32_f16(ah, br[kk], accr, 0, 0, 0);
                accr = __builtin_amdgcn_mfma_f32_16x16x32_f16(al, br[kk], accr, 0, 0, 0);
                accz = __builtin_amdgcn_mfma_f32_16x16x32_f16(ah, bz[kk], accz, 0, 0, 0);
                accz = __builtin_amdgcn_mfma_f32_16x16x32_f16(al, bz[kk], accz, 0, 0, 0);
                accxn = __builtin_amdgcn_mfma_f32_16x16x32_f16(ah, bn[kk], accxn, 0, 0, 0);
                accxn = __builtin_amdgcn_mfma_f32_16x16x32_f16(al, bn[kk], accxn, 0, 0, 0);
            }
            // (barrier B removed — WAR covered by barrier A of t+1; R18-proven)

            // ---- gates + state update + tagged h stores (fire-and-forget) ----
            unsigned* hwp = hbuf + ((size_t)((1 - par) * 2 + d) * B_ + b0) * H_;
            const unsigned tg = ((((unsigned)t) >> 1) & 1u) ^ 1u;
            float yv[4];
            int so4[4];
#pragma unroll
            for (int i = 0; i < 4; ++i) {
                int bl = quad * 4 + i;
                float r = sigm(accr[i] + bias_r);
                float zg = sigm(accz[i] + bias_z);
                float ng = tanhf_((accxn[i] + bihn) + r * (acchn[i] + bhhn));
                float hcand = (1.0f - zg) * ng + zg * h_own[i];
                bool m = (t < len4[i]);
                yv[i] = m ? hcand : 0.0f;
                h_own[i] = m ? hcand : h_own[i];
                _Float16 hhi = (_Float16)h_own[i];
                _Float16 hlo = (_Float16)(h_own[i] - (float)hhi);
                unsigned packed = (unsigned)f16bits(hhi) |
                                  ((((unsigned)f16bits(hlo) & 0xFFFEu) | tg) << 16);
                __hip_atomic_store(hwp + (size_t)bl * H_ + j0w + col, packed,
                                   __ATOMIC_RELAXED, __HIP_MEMORY_SCOPE_AGENT);
                so4[i] = (d && m) ? (len4[i] - 1 - t) : t;
            }
            // ---- Ycat stores: drain overlaps peers' polling ----
#pragma unroll
            for (int i = 0; i < 4; ++i) {
                int bl = quad * 4 + i;
                Ycat[((size_t)(b0 + bl) * S_ + so4[i]) * 1024 + d * 512 + j0w + col] =
                    (_Float16)yv[i];
            }
        } else {
            // whole group masked: zeros at s_out = t; no exchange traffic
#pragma unroll
            for (int i = 0; i < 4; ++i) {
                int bl = quad * 4 + i;
                Ycat[((size_t)(b0 + bl) * S_ + t) * 1024 + d * 512 + j0w + col] = (_Float16)0.0f;
            }
        }
    }
}

// ---------------------------------------------------------------------------
// Final linear as MFMA GEMM: out[pos,l] = blin[l] + sum_c Y[pos,c]*W[l,c].
// [16384 x 1024] x [1024 x 64]. Block = 256 thr (4 waves), covers 64 pos;
// wave covers 16 pos x 64 l (4 n-tiles). A-frags load directly from Ycat
// (f16x8, layout = verified GRU operand pattern); W as hi/lo f16 planes
// (exact fp32 reconstruction). 256 MFMA/wave; grid 256.
// ---------------------------------------------------------------------------
__launch_bounds__(256, 1)
__global__ void lin_kernel(const _Float16* __restrict__ Ycat,
                           const _Float16* __restrict__ Whi,
                           const _Float16* __restrict__ Wlo,
                           const float* __restrict__ blinF,
                           float* __restrict__ out) {
    const int tid = threadIdx.x;
    const int wave = tid >> 6;
    const int lane = tid & 63;
    const int quad = lane >> 4;
    const int col = lane & 15;
    const int pos0 = blockIdx.x * 64 + wave * 16;

    const _Float16* arow = Ycat + (size_t)(pos0 + col) * 1024 + quad * 8;

    f32x4 acc[4] = {{0.f, 0.f, 0.f, 0.f}, {0.f, 0.f, 0.f, 0.f},
                    {0.f, 0.f, 0.f, 0.f}, {0.f, 0.f, 0.f, 0.f}};
#pragma unroll 4
    for (int c = 0; c < 1024; c += 32) {
        f16x8 a = *(const f16x8*)(arow + c);
#pragma unroll
        for (int nt = 0; nt < 4; ++nt) {
            const size_t wo = (size_t)(nt * 16 + col) * 1024 + c + quad * 8;
            f16x8 bh = *(const f16x8*)(Whi + wo);
            f16x8 bl = *(const f16x8*)(Wlo + wo);
            acc[nt] = __builtin_amdgcn_mfma_f32_16x16x32_f16(a, bh, acc[nt], 0, 0, 0);
            acc[nt] = __builtin_amdgcn_mfma_f32_16x16x32_f16(a, bl, acc[nt], 0, 0, 0);
        }
    }
    // C layout: row = quad*4 + reg (pos), col = lane&15 (l within n-tile)
#pragma unroll
    for (int nt = 0; nt < 4; ++nt) {
        int l = nt * 16 + col;
        float bias = blinF[l];
#pragma unroll
        for (int r = 0; r < 4; ++r) {
            int pos = pos0 + quad * 4 + r;
            out[(size_t)pos * L_ + l] = acc[nt][r] + bias;
        }
    }
}

extern "C" void kernel_launch(void* const* d_in, const int* in_sizes, int n_in,
                              void* d_out, int out_size, void* d_ws, size_t ws_size,
                              hipStream_t stream) {
    const int* chars = (const int*)d_in[0];
    const int* lengths = (const int*)d_in[1];
    const void* forget = d_in[2];
    const void* Wihf = d_in[3];
    const void* Whhf = d_in[4];
    const void* bihf = d_in[5];
    const void* bhhf = d_in[6];
    const void* Wihb = d_in[7];
    const void* Whhb = d_in[8];
    const void* bihb = d_in[9];
    const void* bhhb = d_in[10];
    const void* Wlin = d_in[11];
    const void* blin = d_in[12];
    float* out = (float*)d_out;

    char* ws = (char*)d_ws;
    unsigned* hbuf = (unsigned*)(ws + 0);
    unsigned short* xhi = (unsigned short*)(ws + OFF_XHI);
    unsigned short* xlo = (unsigned short*)(ws + OFF_XLO);
    _Float16* whalf = (_Float16*)(ws + OFF_WH);
    float* smallF = (float*)(ws + OFF_SMALL);
    _Float16* Ycat = (_Float16*)(ws + OFF_YCAT);
    _Float16* wlh = (_Float16*)(ws + OFF_WLH);
    _Float16* wll = (_Float16*)(ws + OFF_WLL);

    // fused prep (vectorized): whalf (1920) + small (281) + wlin planes (64)
    // + fofe (8192) + hbuf zeroing (256)
    hipLaunchKernelGGL(prep_all, dim3(10713), dim3(256), 0, stream,
                       Whhf, Whhb, Wihf, Wihb, bihf, bhhf, bihb, bhhb,
                       Wlin, blin, forget, chars,
                       whalf, smallF, wlh, wll, xhi, xlo, hbuf);

    // 16 chains x 8 blocks x 256 threads; tagged fire-and-forget exchange.
    hipLaunchKernelGGL(gru_kernel, dim3(128), dim3(256), 0, stream,
                       lengths, whalf, smallF, xhi, xlo, hbuf, Ycat);

    // MFMA GEMM epilogue: 256 blocks x 64 pos.
    hipLaunchKernelGGL(lin_kernel, dim3(256), dim3(256), 0, stream,
                       Ycat, wlh, wll, smallF + 71680, out);
}